// Round 6
// baseline (1016.698 us; speedup 1.0000x reference)
//
#include <hip/hip_runtime.h>
#include <hip/hip_bf16.h>

// Problem constants
#define B_  2
#define T_  4096
#define DM  1024      // d_model
#define DH  2048      // d_hidden
#define M_  (B_*T_)   // 8192 rows
#define NC  64        // scan chunks
#define CL  64        // chunk length (NC*CL == T_)

typedef __bf16 bf16x8 __attribute__((ext_vector_type(8)));
typedef float  f32x4  __attribute__((ext_vector_type(4)));
typedef unsigned short ushort_t;
typedef unsigned int   uint_t;

__device__ __forceinline__ float sigmoidf_(float v) { return 1.f / (1.f + __expf(-v)); }

// bf16 round-to-nearest-even via bit ops
__device__ __forceinline__ ushort_t f2bf_rne(float x) {
    uint_t u = __float_as_uint(x);
    uint_t r = (u + 0x7fffu + ((u >> 16) & 1u)) >> 16;
    return (ushort_t)r;
}
__device__ __forceinline__ float bf2f(ushort_t h) {
    return __uint_as_float(((uint_t)h) << 16);
}
__device__ __forceinline__ void hl_split(float x, ushort_t& h, ushort_t& l) {
    h = f2bf_rne(x);
    l = f2bf_rne(x - bf2f(h));
}

// ---------------------------------------------------------------------------
// split_hi_lo: fp32 [n*4] -> hi/lo bf16 (same layout)
// ---------------------------------------------------------------------------
__global__ __launch_bounds__(256)
void split_hi_lo(const float* __restrict__ src, ushort_t* __restrict__ hi,
                 ushort_t* __restrict__ lo)
{
    int gid = blockIdx.x * 256 + threadIdx.x;
    float4 v = ((const float4*)src)[gid];
    ushort4 h, l;
    hl_split(v.x, h.x, l.x);
    hl_split(v.y, h.y, l.y);
    hl_split(v.z, h.z, l.z);
    hl_split(v.w, h.w, l.w);
    ((ushort4*)hi)[gid] = h;
    ((ushort4*)lo)[gid] = l;
}

// ---------------------------------------------------------------------------
// split_t: fp32 src[R][C] -> hi/lo bf16 dst[C][R]  (transpose + split)
// grid: (C/32, R/32), 256 threads
// ---------------------------------------------------------------------------
__global__ __launch_bounds__(256)
void split_t(const float* __restrict__ src, ushort_t* __restrict__ dhi,
             ushort_t* __restrict__ dlo, int R, int C)
{
    __shared__ float tile[32][33];
    int tid = threadIdx.x;
    int c0 = blockIdx.x * 32, r0 = blockIdx.y * 32;
    int tr = tid >> 3, tc = (tid & 7) * 4;
    float4 v = *(const float4*)(src + (size_t)(r0 + tr) * C + c0 + tc);
    tile[tc + 0][tr] = v.x;
    tile[tc + 1][tr] = v.y;
    tile[tc + 2][tr] = v.z;
    tile[tc + 3][tr] = v.w;
    __syncthreads();
    int orr = tid >> 3, oc = (tid & 7) * 4;
    ushort4 h, l;
    hl_split(tile[orr][oc + 0], h.x, l.x);
    hl_split(tile[orr][oc + 1], h.y, l.y);
    hl_split(tile[orr][oc + 2], h.z, l.z);
    hl_split(tile[orr][oc + 3], h.w, l.w);
    *(ushort4*)(dhi + (size_t)(c0 + orr) * R + r0 + oc) = h;
    *(ushort4*)(dlo + (size_t)(c0 + orr) * R + r0 + oc) = l;
}

// ---------------------------------------------------------------------------
// mfma_gemm: C[M][N] = A @ Bt^T via bf16 hi/lo split (3 MFMA products).
//   A hi/lo: [M][K] bf16 row-major;  Bt hi/lo: [N][K] bf16 row-major
// Tile 128x128x32, 4 waves (2x2), wave tile 64x64 = 4x4 frags of 16x16x32.
// XOR slot-swizzle (slot ^= (row>>1)&3) on LDS write AND read -> 2-way free.
// Epilogue by ACT (compile-time):
//   0: C0 = acc (+bias)                       [fp32 out]
//   1: C0 = sigmoid(acc + bias)
//   2: C0 = sigmoid(acc + bias) * (1 - aux[m][n])      (alpha from gate)
//   3: u = silu(acc + bias) * aux[m][n]; split -> Uhi/Ulo (no C0)
// N (= out stride = bias range) = gridDim.x*128.
// ---------------------------------------------------------------------------
template<int ACT>
__global__ __launch_bounds__(256)
void mfma_gemm(const ushort_t* __restrict__ Ahg, const ushort_t* __restrict__ Alg,
               const ushort_t* __restrict__ Bhg, const ushort_t* __restrict__ Blg,
               int K,
               float* __restrict__ C0, const float* __restrict__ bias,
               const float* __restrict__ aux,
               ushort_t* __restrict__ Uhi, ushort_t* __restrict__ Ulo)
{
    __shared__ __align__(16) ushort_t Ah[128][32];
    __shared__ __align__(16) ushort_t Al[128][32];
    __shared__ __align__(16) ushort_t Bh[128][32];
    __shared__ __align__(16) ushort_t Bl[128][32];

    const int tid = threadIdx.x;
    // XCD-aware bijective swizzle (all our grids have nwg % 8 == 0)
    int nwg = gridDim.x * gridDim.y;
    int bid = blockIdx.y * gridDim.x + blockIdx.x;
    int swz = (bid & 7) * (nwg >> 3) + (bid >> 3);
    int bx = swz % gridDim.x, by = swz / gridDim.x;
    const int n0 = bx * 128, m0 = by * 128;

    const int r_ = tid >> 2;        // staging row 0..63
    const int s_ = tid & 3;         // staging logical 16B slot
    const int wv = tid >> 6, wr = wv >> 1, wc = wv & 1;
    const int lr = tid & 15, lg = (tid >> 4) & 3;
    const int sl = lg ^ ((lr >> 1) & 3);   // swizzled read slot

    f32x4 acc[4][4];
#pragma unroll
    for (int i = 0; i < 4; i++)
#pragma unroll
        for (int j = 0; j < 4; j++) acc[i][j] = (f32x4){0.f, 0.f, 0.f, 0.f};

    for (int kt = 0; kt < K; kt += 32) {
#pragma unroll
        for (int c = 0; c < 2; c++) {
            int row = r_ + 64 * c;
            size_t ga = (size_t)(m0 + row) * K + kt + s_ * 8;
            size_t gb = (size_t)(n0 + row) * K + kt + s_ * 8;
            uint4 va = *(const uint4*)(Ahg + ga);
            uint4 vb = *(const uint4*)(Alg + ga);
            uint4 vc = *(const uint4*)(Bhg + gb);
            uint4 vd = *(const uint4*)(Blg + gb);
            int sw = (s_ ^ ((row >> 1) & 3)) * 8;
            *(uint4*)&Ah[row][sw] = va;
            *(uint4*)&Al[row][sw] = vb;
            *(uint4*)&Bh[row][sw] = vc;
            *(uint4*)&Bl[row][sw] = vd;
        }
        __syncthreads();
        bf16x8 a_h[4], a_l[4], b_h[4], b_l[4];
#pragma unroll
        for (int i = 0; i < 4; i++) {
            a_h[i] = *(const bf16x8*)&Ah[wr * 64 + i * 16 + lr][sl * 8];
            a_l[i] = *(const bf16x8*)&Al[wr * 64 + i * 16 + lr][sl * 8];
            b_h[i] = *(const bf16x8*)&Bh[wc * 64 + i * 16 + lr][sl * 8];
            b_l[i] = *(const bf16x8*)&Bl[wc * 64 + i * 16 + lr][sl * 8];
        }
#pragma unroll
        for (int i = 0; i < 4; i++)
#pragma unroll
            for (int j = 0; j < 4; j++) {
                acc[i][j] = __builtin_amdgcn_mfma_f32_16x16x32_bf16(a_h[i], b_h[j], acc[i][j], 0, 0, 0);
                acc[i][j] = __builtin_amdgcn_mfma_f32_16x16x32_bf16(a_h[i], b_l[j], acc[i][j], 0, 0, 0);
                acc[i][j] = __builtin_amdgcn_mfma_f32_16x16x32_bf16(a_l[i], b_h[j], acc[i][j], 0, 0, 0);
            }
        __syncthreads();
    }

    const int N = gridDim.x * 128;
#pragma unroll
    for (int i = 0; i < 4; i++)
#pragma unroll
        for (int j = 0; j < 4; j++) {
            int n = n0 + wc * 64 + j * 16 + lr;
            float bv = bias ? bias[n] : 0.f;
#pragma unroll
            for (int rr = 0; rr < 4; rr++) {
                int m = m0 + wr * 64 + i * 16 + lg * 4 + rr;
                float v = acc[i][j][rr] + bv;
                if (ACT == 1) {
                    v = sigmoidf_(v);
                } else if (ACT == 2) {
                    v = sigmoidf_(v) * (1.f - aux[(size_t)m * N + n]);
                } else if (ACT == 3) {
                    float zz = v * sigmoidf_(v);
                    float uu = zz * aux[(size_t)m * N + n];
                    ushort_t uh, ul;
                    hl_split(uu, uh, ul);
                    Uhi[(size_t)m * N + n] = uh;
                    Ulo[(size_t)m * N + n] = ul;
                }
                if (ACT != 3) C0[(size_t)m * N + n] = v;
            }
        }
}

// ---------------------------------------------------------------------------
// conv_beta: beta = gate * causal_conv(ihp), in place over gate.
// ---------------------------------------------------------------------------
__global__ __launch_bounds__(256)
void conv_beta(const float* __restrict__ ihp, float* gate_beta,
               const float* __restrict__ cw, const float* __restrict__ cb)
{
    int gid = blockIdx.x * 256 + threadIdx.x;   // over M_*DH/4
    int c4  = gid & 511;
    int row = gid >> 9;
    int t   = row & (T_ - 1);
    const float4* ih4 = (const float4*)ihp;
    float4 g = ((const float4*)gate_beta)[gid];
    int c0 = c4 * 4;
    float4 w0 = ((const float4*)cw)[c0 + 0];
    float4 w1 = ((const float4*)cw)[c0 + 1];
    float4 w2 = ((const float4*)cw)[c0 + 2];
    float4 w3 = ((const float4*)cw)[c0 + 3];
    float4 cbv = ((const float4*)cb)[c4];
    float4 v[4];
#pragma unroll
    for (int j = 0; j < 4; j++) {
        int tt = t + j - 3;
        if (tt >= 0) v[j] = ih4[(size_t)(row + j - 3) * 512 + c4];
        else         v[j] = make_float4(0.f, 0.f, 0.f, 0.f);
    }
    float4 ihc;
    ihc.x = cbv.x + w0.x * v[0].x + w0.y * v[1].x + w0.z * v[2].x + w0.w * v[3].x;
    ihc.y = cbv.y + w1.x * v[0].y + w1.y * v[1].y + w1.z * v[2].y + w1.w * v[3].y;
    ihc.z = cbv.z + w2.x * v[0].z + w2.y * v[1].z + w2.z * v[2].z + w2.w * v[3].z;
    ihc.w = cbv.w + w3.x * v[0].w + w3.y * v[1].w + w3.z * v[2].w + w3.w * v[3].w;
    float4 beta;
    beta.x = g.x * ihc.x;  beta.y = g.y * ihc.y;
    beta.z = g.z * ihc.z;  beta.w = g.w * ihc.w;
    ((float4*)gate_beta)[gid] = beta;
}

// ---------------------------------------------------------------------------
// 3-phase chunked linear scan: h_t = alpha_t*h_{t-1} + beta_t
// ---------------------------------------------------------------------------
__global__ __launch_bounds__(256)
void scan_phaseA(const float* __restrict__ alpha, const float* __restrict__ beta,
                 float* __restrict__ sA, float* __restrict__ sB)
{
    int gid  = blockIdx.x * 256 + threadIdx.x;   // B_*DH*NC
    int c    = gid & (DH - 1);
    int rest = gid >> 11;
    int chunk = rest & (NC - 1);
    int b    = rest >> 6;
    size_t base = ((size_t)(b * T_ + chunk * CL)) * DH + c;
    float Ar = 1.f, Br = 0.f;
    for (int l = 0; l < CL; l++) {
        float al = alpha[base + (size_t)l * DH];
        float be = beta [base + (size_t)l * DH];
        Ar *= al;
        Br = Br * al + be;
    }
    int si = chunk * (B_ * DH) + b * DH + c;
    sA[si] = Ar; sB[si] = Br;
}

__global__ __launch_bounds__(256)
void scan_phaseB(const float* __restrict__ sA, const float* __restrict__ sB,
                 float* __restrict__ hinit)
{
    int gid = blockIdx.x * 256 + threadIdx.x;    // B_*DH
    int c = gid & (DH - 1); int b = gid >> 11;
    float h = 0.f;
    for (int ch = 0; ch < NC; ch++) {
        int si = ch * (B_ * DH) + b * DH + c;
        hinit[si] = h;
        h = sA[si] * h + sB[si];
    }
}

// phaseC writes h over beta (same buffer) — read-then-write per element.
__global__ __launch_bounds__(256)
void scan_phaseC(const float* __restrict__ alpha, const float* beta,
                 const float* __restrict__ hinit, float* hout)
{
    int gid  = blockIdx.x * 256 + threadIdx.x;
    int c    = gid & (DH - 1);
    int rest = gid >> 11;
    int chunk = rest & (NC - 1);
    int b    = rest >> 6;
    size_t base = ((size_t)(b * T_ + chunk * CL)) * DH + c;
    float h = hinit[chunk * (B_ * DH) + b * DH + c];
    for (int l = 0; l < CL; l++) {
        float al = alpha[base + (size_t)l * DH];
        float be = beta [base + (size_t)l * DH];
        h = al * h + be;
        hout[base + (size_t)l * DH] = h;
    }
}

// ---------------------------------------------------------------------------
// LayerNorm over DH, in place: h -> (h-mu)*rsqrt(var+eps)*g + b
// ---------------------------------------------------------------------------
__global__ __launch_bounds__(256)
void ln_inplace(float* h, const float* __restrict__ g, const float* __restrict__ bl)
{
    int row = blockIdx.x;
    int tid = threadIdx.x;
    float4* h4 = (float4*)(h + (size_t)row * DH);
    float4 v0 = h4[tid], v1 = h4[tid + 256];
    float s = v0.x + v0.y + v0.z + v0.w + v1.x + v1.y + v1.z + v1.w;
    float q = v0.x * v0.x + v0.y * v0.y + v0.z * v0.z + v0.w * v0.w
            + v1.x * v1.x + v1.y * v1.y + v1.z * v1.z + v1.w * v1.w;
#pragma unroll
    for (int o = 32; o; o >>= 1) { s += __shfl_down(s, o); q += __shfl_down(q, o); }
    __shared__ float rs[4], rq[4];
    int wid = tid >> 6, lane = tid & 63;
    if (lane == 0) { rs[wid] = s; rq[wid] = q; }
    __syncthreads();
    s = rs[0] + rs[1] + rs[2] + rs[3];
    q = rq[0] + rq[1] + rq[2] + rq[3];
    float mu  = s * (1.f / DH);
    float var = q * (1.f / DH) - mu * mu;
    float ri  = rsqrtf(var + 1e-5f);
    const float4* g4 = (const float4*)g;
    const float4* b4 = (const float4*)bl;
    {
        float4 gg = g4[tid], bb = b4[tid], o;
        o.x = (v0.x - mu) * ri * gg.x + bb.x;
        o.y = (v0.y - mu) * ri * gg.y + bb.y;
        o.z = (v0.z - mu) * ri * gg.z + bb.z;
        o.w = (v0.w - mu) * ri * gg.w + bb.w;
        h4[tid] = o;
    }
    {
        float4 gg = g4[tid + 256], bb = b4[tid + 256], o;
        o.x = (v1.x - mu) * ri * gg.x + bb.x;
        o.y = (v1.y - mu) * ri * gg.y + bb.y;
        o.z = (v1.z - mu) * ri * gg.z + bb.z;
        o.w = (v1.w - mu) * ri * gg.w + bb.w;
        h4[tid + 256] = o;
    }
}

// Combined output bias: bc = W_out_b @ out_w + out_b
__global__ __launch_bounds__(256)
void bc_kernel(const float* __restrict__ wob, const float* __restrict__ ow,
               const float* __restrict__ ob, float* __restrict__ bc)
{
    int n = blockIdx.x * 256 + threadIdx.x;      // DM
    float acc = ob[n];
    for (int k = 0; k < DH; k++) acc += wob[k] * ow[(size_t)k * DM + n];
    bc[n] = acc;
}

extern "C" void kernel_launch(void* const* d_in, const int* in_sizes, int n_in,
                              void* d_out, int out_size, void* d_ws, size_t ws_size,
                              hipStream_t stream)
{
    const float* x   = (const float*)d_in[0];
    const float* Wih = (const float*)d_in[1];
    const float* bih = (const float*)d_in[2];
    const float* Wg  = (const float*)d_in[3];
    const float* bg  = (const float*)d_in[4];
    const float* Wd  = (const float*)d_in[5];
    const float* bd  = (const float*)d_in[6];
    const float* Wz  = (const float*)d_in[7];
    const float* bz  = (const float*)d_in[8];
    const float* cw  = (const float*)d_in[9];
    const float* cb  = (const float*)d_in[10];
    const float* lng = (const float*)d_in[11];
    const float* lnb = (const float*)d_in[12];
    const float* Wow = (const float*)d_in[13];
    const float* Wob = (const float*)d_in[14];
    const float* ow  = (const float*)d_in[15];
    const float* ob  = (const float*)d_in[16];
    float* out = (float*)d_out;

    // ---- workspace layout: 211 MiB + 4 KiB total ----
    // xhi/xlo (32 MiB) OVERLAY d_out: live steps 1..9; d_out written only in
    // step 10 (after xhi/xlo are dead).  d_out = M_*DM*4B = 32 MiB exactly.
    char* p = (char*)d_ws;
    float* R0 = (float*)(p);                              // 64 MiB: ihp (dead after conv)
    float* R1 = (float*)(p + ((size_t)64  << 20));        // 64 MiB: gate->beta->h->hn
    float* R2 = (float*)(p + ((size_t)128 << 20));        // 64 MiB: alpha (dead after scan)
    ushort_t* Wsh = (ushort_t*)(p + ((size_t)192 << 20)); //  8 MiB (weight slot hi)
    ushort_t* Wsl = (ushort_t*)(p + ((size_t)200 << 20)); //  8 MiB (weight slot lo)
    float* sA    = (float*)(p + ((size_t)208 << 20));     //  1 MiB
    float* sB    = (float*)(p + ((size_t)209 << 20));     //  1 MiB
    float* hinit = (float*)(p + ((size_t)210 << 20));     //  1 MiB
    float* bc    = (float*)(p + ((size_t)211 << 20));     //  4 KiB
    ushort_t* xhi = (ushort_t*)d_out;                            // 16 MiB (overlay)
    ushort_t* xlo = (ushort_t*)((char*)d_out + ((size_t)16 << 20)); // 16 MiB (overlay)
    // R0 sub-region (valid after conv_beta):
    ushort_t* wowh = (ushort_t*)R0;                              // 8 MiB
    ushort_t* wowl = (ushort_t*)((char*)R0 + ((size_t)8  << 20));// 8 MiB
    ushort_t* owth = (ushort_t*)((char*)R0 + ((size_t)16 << 20));// 4 MiB
    ushort_t* owtl = (ushort_t*)((char*)R0 + ((size_t)20 << 20));// 4 MiB
    float*    Wc   = (float*)   ((char*)R0 + ((size_t)24 << 20));// 8 MiB [2048][1024]
    ushort_t* Wcth = (ushort_t*)((char*)R0 + ((size_t)32 << 20));// 4 MiB [1024][2048]
    ushort_t* Wctl = (ushort_t*)((char*)R0 + ((size_t)36 << 20));// 4 MiB
    // R2 sub-region (valid after scan):
    ushort_t* uhi = (ushort_t*)R2;                               // 32 MiB
    ushort_t* ulo = (ushort_t*)((char*)R2 + ((size_t)32 << 20)); // 32 MiB

    // 1. split x -> bf16 hi/lo (into d_out overlay)
    split_hi_lo<<<(M_ * DM / 4) / 256, 256, 0, stream>>>(x, xhi, xlo);

    // 2. ihp = x@Wih + bih (raw preact)
    split_t<<<dim3(DH / 32, DM / 32), 256, 0, stream>>>(Wih, Wsh, Wsl, DM, DH);
    mfma_gemm<0><<<dim3(DH / 128, M_ / 128), 256, 0, stream>>>(
        xhi, xlo, Wsh, Wsl, DM, R0, bih, nullptr, nullptr, nullptr);

    // 3. gate = sigmoid(x@Wg + bg)
    split_t<<<dim3(DH / 32, DM / 32), 256, 0, stream>>>(Wg, Wsh, Wsl, DM, DH);
    mfma_gemm<1><<<dim3(DH / 128, M_ / 128), 256, 0, stream>>>(
        xhi, xlo, Wsh, Wsl, DM, R1, bg, nullptr, nullptr, nullptr);

    // 4. alpha = sigmoid(x@Wd + bd) * (1 - gate)
    split_t<<<dim3(DH / 32, DM / 32), 256, 0, stream>>>(Wd, Wsh, Wsl, DM, DH);
    mfma_gemm<2><<<dim3(DH / 128, M_ / 128), 256, 0, stream>>>(
        xhi, xlo, Wsh, Wsl, DM, R2, bd, R1, nullptr, nullptr);

    // 5. beta = gate * conv(ihp)   (in place over gate; ihp dead after this)
    conv_beta<<<(M_ * DH / 4) / 256, 256, 0, stream>>>(R0, R1, cw, cb);

    // 6. chunked linear scan -> h over beta (R1)
    scan_phaseA<<<(B_ * DH * NC) / 256, 256, 0, stream>>>(R2, R1, sA, sB);
    scan_phaseB<<<(B_ * DH) / 256, 256, 0, stream>>>(sA, sB, hinit);
    scan_phaseC<<<(B_ * DH * NC) / 256, 256, 0, stream>>>(R2, R1, hinit, R1);

    // 7. LayerNorm in place (R1: h -> hn)
    ln_inplace<<<M_, 256, 0, stream>>>(R1, lng, lnb);

    // 8. Wc = Wow @ ow  (folded output weight), bc = Wob@ow + ob
    split_hi_lo<<<((size_t)DH * DH / 4) / 256, 256, 0, stream>>>(Wow, wowh, wowl);
    split_t<<<dim3(DM / 32, DH / 32), 256, 0, stream>>>(ow, owth, owtl, DH, DM);
    mfma_gemm<0><<<dim3(DM / 128, DH / 128), 256, 0, stream>>>(
        wowh, wowl, owth, owtl, DH, Wc, nullptr, nullptr, nullptr, nullptr);
    split_t<<<dim3(DM / 32, DH / 32), 256, 0, stream>>>(Wc, Wcth, Wctl, DH, DM);
    bc_kernel<<<DM / 256, 256, 0, stream>>>(Wob, ow, ob, bc);

    // 9. z GEMM fused: u = silu(x@Wz + bz) * hn, split -> uhi/ulo (over R2)
    split_t<<<dim3(DH / 32, DM / 32), 256, 0, stream>>>(Wz, Wsh, Wsl, DM, DH);
    mfma_gemm<3><<<dim3(DH / 128, M_ / 128), 256, 0, stream>>>(
        xhi, xlo, Wsh, Wsl, DM, nullptr, bz, R1, uhi, ulo);

    // 10. out = u @ Wc + bc   (xhi/xlo dead; d_out now becomes the real output)
    mfma_gemm<0><<<dim3(DM / 128, M_ / 128), 256, 0, stream>>>(
        uhi, ulo, Wcth, Wctl, DH, out, bc, nullptr, nullptr, nullptr);
}

// Round 7
// 998.371 us; speedup vs baseline: 1.0184x; 1.0184x over previous
//
#include <hip/hip_runtime.h>
#include <hip/hip_bf16.h>

// Problem constants
#define B_  2
#define T_  4096
#define DM  1024      // d_model
#define DH  2048      // d_hidden
#define M_  (B_*T_)   // 8192 rows
#define NC  64        // scan chunks
#define CL  64        // chunk length (NC*CL == T_)

typedef __bf16 bf16x8 __attribute__((ext_vector_type(8)));
typedef float  f32x4  __attribute__((ext_vector_type(4)));
typedef unsigned short ushort_t;
typedef unsigned int   uint_t;

__device__ __forceinline__ float sigmoidf_(float v) { return 1.f / (1.f + __expf(-v)); }

// bf16 round-to-nearest-even via bit ops
__device__ __forceinline__ ushort_t f2bf_rne(float x) {
    uint_t u = __float_as_uint(x);
    uint_t r = (u + 0x7fffu + ((u >> 16) & 1u)) >> 16;
    return (ushort_t)r;
}
__device__ __forceinline__ float bf2f(ushort_t h) {
    return __uint_as_float(((uint_t)h) << 16);
}
__device__ __forceinline__ void hl_split(float x, ushort_t& h, ushort_t& l) {
    h = f2bf_rne(x);
    l = f2bf_rne(x - bf2f(h));
}

// async global->LDS, 16B per lane; lds base must be wave-uniform (HW adds lane*16)
__device__ __forceinline__ void gload16(const ushort_t* g, ushort_t* l) {
    __builtin_amdgcn_global_load_lds((const __attribute__((address_space(1))) void*)g,
                                     (__attribute__((address_space(3))) void*)l,
                                     16, 0, 0);
}

// ---------------------------------------------------------------------------
// split_hi_lo: fp32 [n*4] -> hi/lo bf16 (same layout)
// ---------------------------------------------------------------------------
__global__ __launch_bounds__(256)
void split_hi_lo(const float* __restrict__ src, ushort_t* __restrict__ hi,
                 ushort_t* __restrict__ lo)
{
    int gid = blockIdx.x * 256 + threadIdx.x;
    float4 v = ((const float4*)src)[gid];
    ushort4 h, l;
    hl_split(v.x, h.x, l.x);
    hl_split(v.y, h.y, l.y);
    hl_split(v.z, h.z, l.z);
    hl_split(v.w, h.w, l.w);
    ((ushort4*)hi)[gid] = h;
    ((ushort4*)lo)[gid] = l;
}

// ---------------------------------------------------------------------------
// split_t: fp32 src[R][C] -> hi/lo bf16 dst[C][R]  (transpose + split)
// grid: (C/32, R/32), 256 threads
// ---------------------------------------------------------------------------
__global__ __launch_bounds__(256)
void split_t(const float* __restrict__ src, ushort_t* __restrict__ dhi,
             ushort_t* __restrict__ dlo, int R, int C)
{
    __shared__ float tile[32][33];
    int tid = threadIdx.x;
    int c0 = blockIdx.x * 32, r0 = blockIdx.y * 32;
    int tr = tid >> 3, tc = (tid & 7) * 4;
    float4 v = *(const float4*)(src + (size_t)(r0 + tr) * C + c0 + tc);
    tile[tc + 0][tr] = v.x;
    tile[tc + 1][tr] = v.y;
    tile[tc + 2][tr] = v.z;
    tile[tc + 3][tr] = v.w;
    __syncthreads();
    int orr = tid >> 3, oc = (tid & 7) * 4;
    ushort4 h, l;
    hl_split(tile[orr][oc + 0], h.x, l.x);
    hl_split(tile[orr][oc + 1], h.y, l.y);
    hl_split(tile[orr][oc + 2], h.z, l.z);
    hl_split(tile[orr][oc + 3], h.w, l.w);
    *(ushort4*)(dhi + (size_t)(c0 + orr) * R + r0 + oc) = h;
    *(ushort4*)(dlo + (size_t)(c0 + orr) * R + r0 + oc) = l;
}

// ---------------------------------------------------------------------------
// mfma_gemm: C[M][N] = A @ Bt^T via bf16 hi/lo split (3 MFMA products).
//   A hi/lo: [M][K] bf16 row-major;  Bt hi/lo: [N][K] bf16 row-major
// Tile 128x128x32, 4 waves (2x2), wave tile 64x64 = 4x4 frags of 16x16x32.
// Staging via global_load_lds (16B/lane, linear LDS dest); the XOR slot
// swizzle is applied by PRE-SWIZZLING the global source slot, so
// LDS[row][q] = G[row][q ^ ((row>>1)&3)] — identical layout to reg-staged
// version; read path applies the same XOR. Bank-conflict-free (measured 0).
// Epilogue by ACT (compile-time):
//   0: C0 = acc (+bias)                       [fp32 out]
//   1: C0 = sigmoid(acc + bias)
//   2: C0 = sigmoid(acc + bias) * (1 - aux[m][n])      (alpha from gate)
//   3: u = silu(acc + bias) * aux[m][n]; split -> Uhi/Ulo (no C0)
// N (= out stride = bias range) = gridDim.x*128.
// ---------------------------------------------------------------------------
template<int ACT>
__global__ __launch_bounds__(256)
void mfma_gemm(const ushort_t* __restrict__ Ahg, const ushort_t* __restrict__ Alg,
               const ushort_t* __restrict__ Bhg, const ushort_t* __restrict__ Blg,
               int K,
               float* __restrict__ C0, const float* __restrict__ bias,
               const float* __restrict__ aux,
               ushort_t* __restrict__ Uhi, ushort_t* __restrict__ Ulo)
{
    __shared__ __align__(16) ushort_t Ah[128][32];
    __shared__ __align__(16) ushort_t Al[128][32];
    __shared__ __align__(16) ushort_t Bh[128][32];
    __shared__ __align__(16) ushort_t Bl[128][32];

    const int tid = threadIdx.x;
    // XCD-aware bijective swizzle (all our grids have nwg % 8 == 0)
    int nwg = gridDim.x * gridDim.y;
    int bid = blockIdx.y * gridDim.x + blockIdx.x;
    int swz = (bid & 7) * (nwg >> 3) + (bid >> 3);
    int bx = swz % gridDim.x, by = swz / gridDim.x;
    const int n0 = bx * 128, m0 = by * 128;

    const int r_ = tid >> 2;        // staging row 0..63
    const int s_ = tid & 3;         // staging lane slot (16B units)
    const int wv = tid >> 6, wr = wv >> 1, wc = wv & 1;
    const int lr = tid & 15, lg = (tid >> 4) & 3;
    const int sl = lg ^ ((lr >> 1) & 3);   // swizzled read slot

    f32x4 acc[4][4];
#pragma unroll
    for (int i = 0; i < 4; i++)
#pragma unroll
        for (int j = 0; j < 4; j++) acc[i][j] = (f32x4){0.f, 0.f, 0.f, 0.f};

    for (int kt = 0; kt < K; kt += 32) {
#pragma unroll
        for (int c = 0; c < 2; c++) {
            const int row   = r_ + (c << 6);          // per-lane row
            const int sslot = s_ ^ ((row >> 1) & 3);  // pre-swizzled source slot
            const size_t ga = (size_t)(m0 + row) * K + kt + (sslot << 3);
            const size_t gb = (size_t)(n0 + row) * K + kt + (sslot << 3);
            const int lrow  = (wv << 4) + (c << 6);   // wave-uniform LDS base row
            gload16(Ahg + ga, &Ah[lrow][0]);
            gload16(Alg + ga, &Al[lrow][0]);
            gload16(Bhg + gb, &Bh[lrow][0]);
            gload16(Blg + gb, &Bl[lrow][0]);
        }
        __syncthreads();
        bf16x8 a_h[4], a_l[4], b_h[4], b_l[4];
#pragma unroll
        for (int i = 0; i < 4; i++) {
            a_h[i] = *(const bf16x8*)&Ah[wr * 64 + i * 16 + lr][sl * 8];
            a_l[i] = *(const bf16x8*)&Al[wr * 64 + i * 16 + lr][sl * 8];
            b_h[i] = *(const bf16x8*)&Bh[wc * 64 + i * 16 + lr][sl * 8];
            b_l[i] = *(const bf16x8*)&Bl[wc * 64 + i * 16 + lr][sl * 8];
        }
#pragma unroll
        for (int i = 0; i < 4; i++)
#pragma unroll
            for (int j = 0; j < 4; j++) {
                acc[i][j] = __builtin_amdgcn_mfma_f32_16x16x32_bf16(a_h[i], b_h[j], acc[i][j], 0, 0, 0);
                acc[i][j] = __builtin_amdgcn_mfma_f32_16x16x32_bf16(a_h[i], b_l[j], acc[i][j], 0, 0, 0);
                acc[i][j] = __builtin_amdgcn_mfma_f32_16x16x32_bf16(a_l[i], b_h[j], acc[i][j], 0, 0, 0);
            }
        __syncthreads();
    }

    const int N = gridDim.x * 128;
#pragma unroll
    for (int i = 0; i < 4; i++)
#pragma unroll
        for (int j = 0; j < 4; j++) {
            int n = n0 + wc * 64 + j * 16 + lr;
            float bv = bias ? bias[n] : 0.f;
#pragma unroll
            for (int rr = 0; rr < 4; rr++) {
                int m = m0 + wr * 64 + i * 16 + lg * 4 + rr;
                float v = acc[i][j][rr] + bv;
                if (ACT == 1) {
                    v = sigmoidf_(v);
                } else if (ACT == 2) {
                    v = sigmoidf_(v) * (1.f - aux[(size_t)m * N + n]);
                } else if (ACT == 3) {
                    float zz = v * sigmoidf_(v);
                    float uu = zz * aux[(size_t)m * N + n];
                    ushort_t uh, ul;
                    hl_split(uu, uh, ul);
                    Uhi[(size_t)m * N + n] = uh;
                    Ulo[(size_t)m * N + n] = ul;
                }
                if (ACT != 3) C0[(size_t)m * N + n] = v;
            }
        }
}

// ---------------------------------------------------------------------------
// conv_beta: beta = gate * causal_conv(ihp), in place over gate.
// ---------------------------------------------------------------------------
__global__ __launch_bounds__(256)
void conv_beta(const float* __restrict__ ihp, float* gate_beta,
               const float* __restrict__ cw, const float* __restrict__ cb)
{
    int gid = blockIdx.x * 256 + threadIdx.x;   // over M_*DH/4
    int c4  = gid & 511;
    int row = gid >> 9;
    int t   = row & (T_ - 1);
    const float4* ih4 = (const float4*)ihp;
    float4 g = ((const float4*)gate_beta)[gid];
    int c0 = c4 * 4;
    float4 w0 = ((const float4*)cw)[c0 + 0];
    float4 w1 = ((const float4*)cw)[c0 + 1];
    float4 w2 = ((const float4*)cw)[c0 + 2];
    float4 w3 = ((const float4*)cw)[c0 + 3];
    float4 cbv = ((const float4*)cb)[c4];
    float4 v[4];
#pragma unroll
    for (int j = 0; j < 4; j++) {
        int tt = t + j - 3;
        if (tt >= 0) v[j] = ih4[(size_t)(row + j - 3) * 512 + c4];
        else         v[j] = make_float4(0.f, 0.f, 0.f, 0.f);
    }
    float4 ihc;
    ihc.x = cbv.x + w0.x * v[0].x + w0.y * v[1].x + w0.z * v[2].x + w0.w * v[3].x;
    ihc.y = cbv.y + w1.x * v[0].y + w1.y * v[1].y + w1.z * v[2].y + w1.w * v[3].y;
    ihc.z = cbv.z + w2.x * v[0].z + w2.y * v[1].z + w2.z * v[2].z + w2.w * v[3].z;
    ihc.w = cbv.w + w3.x * v[0].w + w3.y * v[1].w + w3.z * v[2].w + w3.w * v[3].w;
    float4 beta;
    beta.x = g.x * ihc.x;  beta.y = g.y * ihc.y;
    beta.z = g.z * ihc.z;  beta.w = g.w * ihc.w;
    ((float4*)gate_beta)[gid] = beta;
}

// ---------------------------------------------------------------------------
// 3-phase chunked linear scan: h_t = alpha_t*h_{t-1} + beta_t
// ---------------------------------------------------------------------------
__global__ __launch_bounds__(256)
void scan_phaseA(const float* __restrict__ alpha, const float* __restrict__ beta,
                 float* __restrict__ sA, float* __restrict__ sB)
{
    int gid  = blockIdx.x * 256 + threadIdx.x;   // B_*DH*NC
    int c    = gid & (DH - 1);
    int rest = gid >> 11;
    int chunk = rest & (NC - 1);
    int b    = rest >> 6;
    size_t base = ((size_t)(b * T_ + chunk * CL)) * DH + c;
    float Ar = 1.f, Br = 0.f;
    for (int l = 0; l < CL; l++) {
        float al = alpha[base + (size_t)l * DH];
        float be = beta [base + (size_t)l * DH];
        Ar *= al;
        Br = Br * al + be;
    }
    int si = chunk * (B_ * DH) + b * DH + c;
    sA[si] = Ar; sB[si] = Br;
}

__global__ __launch_bounds__(256)
void scan_phaseB(const float* __restrict__ sA, const float* __restrict__ sB,
                 float* __restrict__ hinit)
{
    int gid = blockIdx.x * 256 + threadIdx.x;    // B_*DH
    int c = gid & (DH - 1); int b = gid >> 11;
    float h = 0.f;
    for (int ch = 0; ch < NC; ch++) {
        int si = ch * (B_ * DH) + b * DH + c;
        hinit[si] = h;
        h = sA[si] * h + sB[si];
    }
}

// phaseC writes h over beta (same buffer) — read-then-write per element.
__global__ __launch_bounds__(256)
void scan_phaseC(const float* __restrict__ alpha, const float* beta,
                 const float* __restrict__ hinit, float* hout)
{
    int gid  = blockIdx.x * 256 + threadIdx.x;
    int c    = gid & (DH - 1);
    int rest = gid >> 11;
    int chunk = rest & (NC - 1);
    int b    = rest >> 6;
    size_t base = ((size_t)(b * T_ + chunk * CL)) * DH + c;
    float h = hinit[chunk * (B_ * DH) + b * DH + c];
    for (int l = 0; l < CL; l++) {
        float al = alpha[base + (size_t)l * DH];
        float be = beta [base + (size_t)l * DH];
        h = al * h + be;
        hout[base + (size_t)l * DH] = h;
    }
}

// ---------------------------------------------------------------------------
// LayerNorm over DH, in place: h -> (h-mu)*rsqrt(var+eps)*g + b
// ---------------------------------------------------------------------------
__global__ __launch_bounds__(256)
void ln_inplace(float* h, const float* __restrict__ g, const float* __restrict__ bl)
{
    int row = blockIdx.x;
    int tid = threadIdx.x;
    float4* h4 = (float4*)(h + (size_t)row * DH);
    float4 v0 = h4[tid], v1 = h4[tid + 256];
    float s = v0.x + v0.y + v0.z + v0.w + v1.x + v1.y + v1.z + v1.w;
    float q = v0.x * v0.x + v0.y * v0.y + v0.z * v0.z + v0.w * v0.w
            + v1.x * v1.x + v1.y * v1.y + v1.z * v1.z + v1.w * v1.w;
#pragma unroll
    for (int o = 32; o; o >>= 1) { s += __shfl_down(s, o); q += __shfl_down(q, o); }
    __shared__ float rs[4], rq[4];
    int wid = tid >> 6, lane = tid & 63;
    if (lane == 0) { rs[wid] = s; rq[wid] = q; }
    __syncthreads();
    s = rs[0] + rs[1] + rs[2] + rs[3];
    q = rq[0] + rq[1] + rq[2] + rq[3];
    float mu  = s * (1.f / DH);
    float var = q * (1.f / DH) - mu * mu;
    float ri  = rsqrtf(var + 1e-5f);
    const float4* g4 = (const float4*)g;
    const float4* b4 = (const float4*)bl;
    {
        float4 gg = g4[tid], bb = b4[tid], o;
        o.x = (v0.x - mu) * ri * gg.x + bb.x;
        o.y = (v0.y - mu) * ri * gg.y + bb.y;
        o.z = (v0.z - mu) * ri * gg.z + bb.z;
        o.w = (v0.w - mu) * ri * gg.w + bb.w;
        h4[tid] = o;
    }
    {
        float4 gg = g4[tid + 256], bb = b4[tid + 256], o;
        o.x = (v1.x - mu) * ri * gg.x + bb.x;
        o.y = (v1.y - mu) * ri * gg.y + bb.y;
        o.z = (v1.z - mu) * ri * gg.z + bb.z;
        o.w = (v1.w - mu) * ri * gg.w + bb.w;
        h4[tid + 256] = o;
    }
}

// Combined output bias: bc = W_out_b @ out_w + out_b
__global__ __launch_bounds__(256)
void bc_kernel(const float* __restrict__ wob, const float* __restrict__ ow,
               const float* __restrict__ ob, float* __restrict__ bc)
{
    int n = blockIdx.x * 256 + threadIdx.x;      // DM
    float acc = ob[n];
    for (int k = 0; k < DH; k++) acc += wob[k] * ow[(size_t)k * DM + n];
    bc[n] = acc;
}

extern "C" void kernel_launch(void* const* d_in, const int* in_sizes, int n_in,
                              void* d_out, int out_size, void* d_ws, size_t ws_size,
                              hipStream_t stream)
{
    const float* x   = (const float*)d_in[0];
    const float* Wih = (const float*)d_in[1];
    const float* bih = (const float*)d_in[2];
    const float* Wg  = (const float*)d_in[3];
    const float* bg  = (const float*)d_in[4];
    const float* Wd  = (const float*)d_in[5];
    const float* bd  = (const float*)d_in[6];
    const float* Wz  = (const float*)d_in[7];
    const float* bz  = (const float*)d_in[8];
    const float* cw  = (const float*)d_in[9];
    const float* cb  = (const float*)d_in[10];
    const float* lng = (const float*)d_in[11];
    const float* lnb = (const float*)d_in[12];
    const float* Wow = (const float*)d_in[13];
    const float* Wob = (const float*)d_in[14];
    const float* ow  = (const float*)d_in[15];
    const float* ob  = (const float*)d_in[16];
    float* out = (float*)d_out;

    // ---- workspace layout: 211 MiB + 4 KiB total ----
    // xhi/xlo (32 MiB) OVERLAY d_out: live steps 1..9; d_out written only in
    // step 10 (after xhi/xlo are dead).  d_out = M_*DM*4B = 32 MiB exactly.
    char* p = (char*)d_ws;
    float* R0 = (float*)(p);                              // 64 MiB: ihp (dead after conv)
    float* R1 = (float*)(p + ((size_t)64  << 20));        // 64 MiB: gate->beta->h->hn
    float* R2 = (float*)(p + ((size_t)128 << 20));        // 64 MiB: alpha (dead after scan)
    ushort_t* Wsh = (ushort_t*)(p + ((size_t)192 << 20)); //  8 MiB (weight slot hi)
    ushort_t* Wsl = (ushort_t*)(p + ((size_t)200 << 20)); //  8 MiB (weight slot lo)
    float* sA    = (float*)(p + ((size_t)208 << 20));     //  1 MiB
    float* sB    = (float*)(p + ((size_t)209 << 20));     //  1 MiB
    float* hinit = (float*)(p + ((size_t)210 << 20));     //  1 MiB
    float* bc    = (float*)(p + ((size_t)211 << 20));     //  4 KiB
    ushort_t* xhi = (ushort_t*)d_out;                            // 16 MiB (overlay)
    ushort_t* xlo = (ushort_t*)((char*)d_out + ((size_t)16 << 20)); // 16 MiB (overlay)
    // R0 sub-region (valid after conv_beta):
    ushort_t* wowh = (ushort_t*)R0;                              // 8 MiB
    ushort_t* wowl = (ushort_t*)((char*)R0 + ((size_t)8  << 20));// 8 MiB
    ushort_t* owth = (ushort_t*)((char*)R0 + ((size_t)16 << 20));// 4 MiB
    ushort_t* owtl = (ushort_t*)((char*)R0 + ((size_t)20 << 20));// 4 MiB
    float*    Wc   = (float*)   ((char*)R0 + ((size_t)24 << 20));// 8 MiB [2048][1024]
    ushort_t* Wcth = (ushort_t*)((char*)R0 + ((size_t)32 << 20));// 4 MiB [1024][2048]
    ushort_t* Wctl = (ushort_t*)((char*)R0 + ((size_t)36 << 20));// 4 MiB
    // R2 sub-region (valid after scan):
    ushort_t* uhi = (ushort_t*)R2;                               // 32 MiB
    ushort_t* ulo = (ushort_t*)((char*)R2 + ((size_t)32 << 20)); // 32 MiB

    // 1. split x -> bf16 hi/lo (into d_out overlay)
    split_hi_lo<<<(M_ * DM / 4) / 256, 256, 0, stream>>>(x, xhi, xlo);

    // 2. ihp = x@Wih + bih (raw preact)
    split_t<<<dim3(DH / 32, DM / 32), 256, 0, stream>>>(Wih, Wsh, Wsl, DM, DH);
    mfma_gemm<0><<<dim3(DH / 128, M_ / 128), 256, 0, stream>>>(
        xhi, xlo, Wsh, Wsl, DM, R0, bih, nullptr, nullptr, nullptr);

    // 3. gate = sigmoid(x@Wg + bg)
    split_t<<<dim3(DH / 32, DM / 32), 256, 0, stream>>>(Wg, Wsh, Wsl, DM, DH);
    mfma_gemm<1><<<dim3(DH / 128, M_ / 128), 256, 0, stream>>>(
        xhi, xlo, Wsh, Wsl, DM, R1, bg, nullptr, nullptr, nullptr);

    // 4. alpha = sigmoid(x@Wd + bd) * (1 - gate)
    split_t<<<dim3(DH / 32, DM / 32), 256, 0, stream>>>(Wd, Wsh, Wsl, DM, DH);
    mfma_gemm<2><<<dim3(DH / 128, M_ / 128), 256, 0, stream>>>(
        xhi, xlo, Wsh, Wsl, DM, R2, bd, R1, nullptr, nullptr);

    // 5. beta = gate * conv(ihp)   (in place over gate; ihp dead after this)
    conv_beta<<<(M_ * DH / 4) / 256, 256, 0, stream>>>(R0, R1, cw, cb);

    // 6. chunked linear scan -> h over beta (R1)
    scan_phaseA<<<(B_ * DH * NC) / 256, 256, 0, stream>>>(R2, R1, sA, sB);
    scan_phaseB<<<(B_ * DH) / 256, 256, 0, stream>>>(sA, sB, hinit);
    scan_phaseC<<<(B_ * DH * NC) / 256, 256, 0, stream>>>(R2, R1, hinit, R1);

    // 7. LayerNorm in place (R1: h -> hn)
    ln_inplace<<<M_, 256, 0, stream>>>(R1, lng, lnb);

    // 8. Wc = Wow @ ow  (folded output weight), bc = Wob@ow + ob
    split_hi_lo<<<((size_t)DH * DH / 4) / 256, 256, 0, stream>>>(Wow, wowh, wowl);
    split_t<<<dim3(DM / 32, DH / 32), 256, 0, stream>>>(ow, owth, owtl, DH, DM);
    mfma_gemm<0><<<dim3(DM / 128, DH / 128), 256, 0, stream>>>(
        wowh, wowl, owth, owtl, DH, Wc, nullptr, nullptr, nullptr, nullptr);
    split_t<<<dim3(DM / 32, DH / 32), 256, 0, stream>>>(Wc, Wcth, Wctl, DH, DM);
    bc_kernel<<<DM / 256, 256, 0, stream>>>(Wob, ow, ob, bc);

    // 9. z GEMM fused: u = silu(x@Wz + bz) * hn, split -> uhi/ulo (over R2)
    split_t<<<dim3(DH / 32, DM / 32), 256, 0, stream>>>(Wz, Wsh, Wsl, DM, DH);
    mfma_gemm<3><<<dim3(DH / 128, M_ / 128), 256, 0, stream>>>(
        xhi, xlo, Wsh, Wsl, DM, nullptr, bz, R1, uhi, ulo);

    // 10. out = u @ Wc + bc   (xhi/xlo dead; d_out now becomes the real output)
    mfma_gemm<0><<<dim3(DM / 128, M_ / 128), 256, 0, stream>>>(
        uhi, ulo, Wcth, Wctl, DH, out, bc, nullptr, nullptr, nullptr);
}

// Round 9
// 929.392 us; speedup vs baseline: 1.0939x; 1.0742x over previous
//
#include <hip/hip_runtime.h>
#include <hip/hip_bf16.h>

// Problem constants
#define B_  2
#define T_  4096
#define DM  1024      // d_model
#define DH  2048      // d_hidden
#define M_  (B_*T_)   // 8192 rows
#define NC  64        // scan chunks
#define CL  64        // chunk length (NC*CL == T_)

typedef __bf16 bf16x8 __attribute__((ext_vector_type(8)));
typedef float  f32x4  __attribute__((ext_vector_type(4)));
typedef unsigned short ushort_t;
typedef unsigned int   uint_t;

__device__ __forceinline__ float sigmoidf_(float v) { return 1.f / (1.f + __expf(-v)); }

// bf16 round-to-nearest-even via bit ops
__device__ __forceinline__ ushort_t f2bf_rne(float x) {
    uint_t u = __float_as_uint(x);
    uint_t r = (u + 0x7fffu + ((u >> 16) & 1u)) >> 16;
    return (ushort_t)r;
}
__device__ __forceinline__ float bf2f(ushort_t h) {
    return __uint_as_float(((uint_t)h) << 16);
}
__device__ __forceinline__ void hl_split(float x, ushort_t& h, ushort_t& l) {
    h = f2bf_rne(x);
    l = f2bf_rne(x - bf2f(h));
}

// async global->LDS, 16B per lane; lds base must be wave-uniform (HW adds lane*16)
__device__ __forceinline__ void gload16(const ushort_t* g, ushort_t* l) {
    __builtin_amdgcn_global_load_lds((const __attribute__((address_space(1))) void*)g,
                                     (__attribute__((address_space(3))) void*)l,
                                     16, 0, 0);
}

// ---------------------------------------------------------------------------
// split_hi_lo: fp32 [n*4] -> hi/lo bf16 (same layout)
// ---------------------------------------------------------------------------
__global__ __launch_bounds__(256)
void split_hi_lo(const float* __restrict__ src, ushort_t* __restrict__ hi,
                 ushort_t* __restrict__ lo)
{
    int gid = blockIdx.x * 256 + threadIdx.x;
    float4 v = ((const float4*)src)[gid];
    ushort4 h, l;
    hl_split(v.x, h.x, l.x);
    hl_split(v.y, h.y, l.y);
    hl_split(v.z, h.z, l.z);
    hl_split(v.w, h.w, l.w);
    ((ushort4*)hi)[gid] = h;
    ((ushort4*)lo)[gid] = l;
}

// ---------------------------------------------------------------------------
// split_t: fp32 src[R][C] -> hi/lo bf16 dst[C][R]  (transpose + split)
// grid: (C/32, R/32), 256 threads
// ---------------------------------------------------------------------------
__global__ __launch_bounds__(256)
void split_t(const float* __restrict__ src, ushort_t* __restrict__ dhi,
             ushort_t* __restrict__ dlo, int R, int C)
{
    __shared__ float tile[32][33];
    int tid = threadIdx.x;
    int c0 = blockIdx.x * 32, r0 = blockIdx.y * 32;
    int tr = tid >> 3, tc = (tid & 7) * 4;
    float4 v = *(const float4*)(src + (size_t)(r0 + tr) * C + c0 + tc);
    tile[tc + 0][tr] = v.x;
    tile[tc + 1][tr] = v.y;
    tile[tc + 2][tr] = v.z;
    tile[tc + 3][tr] = v.w;
    __syncthreads();
    int orr = tid >> 3, oc = (tid & 7) * 4;
    ushort4 h, l;
    hl_split(tile[orr][oc + 0], h.x, l.x);
    hl_split(tile[orr][oc + 1], h.y, l.y);
    hl_split(tile[orr][oc + 2], h.z, l.z);
    hl_split(tile[orr][oc + 3], h.w, l.w);
    *(ushort4*)(dhi + (size_t)(c0 + orr) * R + r0 + oc) = h;
    *(ushort4*)(dlo + (size_t)(c0 + orr) * R + r0 + oc) = l;
}

// ---------------------------------------------------------------------------
// mfma_gemm: C[M][N] = A @ Bt^T via bf16 hi/lo split (3 MFMA products).
//   A hi/lo: [M][K] bf16 row-major;  Bt hi/lo: [N][K] bf16 row-major
// Tile 128x128x32, 4 waves (2x2), wave tile 64x64 = 4x4 frags of 16x16x32.
// DOUBLE-BUFFERED staging via global_load_lds (16B/lane, linear LDS dest):
// tile t+1's loads are issued BEFORE tile t's compute; the __syncthreads at
// loop end drains them (vmcnt 0) and fences buffer reuse. 1-deep pipeline —
// load latency overlaps MFMA+ds_read instead of serializing (T3-minimum).
// XOR slot swizzle via PRE-SWIZZLED global source slot:
// LDS[row][q] = G[row][q ^ ((row>>1)&3)]; read applies the same XOR.
// Epilogue by ACT (compile-time):
//   0: C0 = acc (+bias)                       [fp32 out]
//   1: C0 = sigmoid(acc + bias)
//   2: C0 = sigmoid(acc + bias) * (1 - aux[m][n])      (alpha from gate)
//   3: u = silu(acc + bias) * aux[m][n]; split -> Uhi/Ulo (no C0)
// N (= out stride = bias range) = gridDim.x*128.
// ---------------------------------------------------------------------------
template<int ACT>
__global__ __launch_bounds__(256)
void mfma_gemm(const ushort_t* __restrict__ Ahg, const ushort_t* __restrict__ Alg,
               const ushort_t* __restrict__ Bhg, const ushort_t* __restrict__ Blg,
               int K,
               float* __restrict__ C0, const float* __restrict__ bias,
               const float* __restrict__ aux,
               ushort_t* __restrict__ Uhi, ushort_t* __restrict__ Ulo)
{
    __shared__ __align__(16) ushort_t Ah[2][128][32];
    __shared__ __align__(16) ushort_t Al[2][128][32];
    __shared__ __align__(16) ushort_t Bh[2][128][32];
    __shared__ __align__(16) ushort_t Bl[2][128][32];

    const int tid = threadIdx.x;
    // XCD-aware bijective swizzle (all our grids have nwg % 8 == 0)
    int nwg = gridDim.x * gridDim.y;
    int bid = blockIdx.y * gridDim.x + blockIdx.x;
    int swz = (bid & 7) * (nwg >> 3) + (bid >> 3);
    int bx = swz % gridDim.x, by = swz / gridDim.x;
    const int n0 = bx * 128, m0 = by * 128;

    const int r_ = tid >> 2;        // staging row 0..63
    const int s_ = tid & 3;         // staging lane slot (16B units)
    // (row>>1)&3 is independent of the 64-row half: ((r_+64c)>>1)&3 == (r_>>1)&3
    const int sslot = s_ ^ ((r_ >> 1) & 3);   // pre-swizzled source slot
    const int wv = tid >> 6, wr = wv >> 1, wc = wv & 1;
    const int lr = tid & 15, lg = (tid >> 4) & 3;
    const int sl = lg ^ ((lr >> 1) & 3);      // swizzled read slot

    auto STAGE = [&](int buf, int kt) {
#pragma unroll
        for (int c = 0; c < 2; c++) {
            const size_t ga = (size_t)(m0 + r_ + (c << 6)) * K + kt + (sslot << 3);
            const size_t gb = (size_t)(n0 + r_ + (c << 6)) * K + kt + (sslot << 3);
            const int lrow  = (wv << 4) + (c << 6);   // wave-uniform LDS base row
            gload16(Ahg + ga, &Ah[buf][lrow][0]);
            gload16(Alg + ga, &Al[buf][lrow][0]);
            gload16(Bhg + gb, &Bh[buf][lrow][0]);
            gload16(Blg + gb, &Bl[buf][lrow][0]);
        }
    };

    f32x4 acc[4][4];
#pragma unroll
    for (int i = 0; i < 4; i++)
#pragma unroll
        for (int j = 0; j < 4; j++) acc[i][j] = (f32x4){0.f, 0.f, 0.f, 0.f};

    const int nT = K >> 5;
    STAGE(0, 0);
    __syncthreads();

    int cur = 0;
    for (int t = 0; t < nT; ++t) {
        if (t + 1 < nT) STAGE(cur ^ 1, (t + 1) << 5);   // async prefetch next tile
        bf16x8 a_h[4], a_l[4], b_h[4], b_l[4];
#pragma unroll
        for (int i = 0; i < 4; i++) {
            a_h[i] = *(const bf16x8*)&Ah[cur][wr * 64 + i * 16 + lr][sl * 8];
            a_l[i] = *(const bf16x8*)&Al[cur][wr * 64 + i * 16 + lr][sl * 8];
            b_h[i] = *(const bf16x8*)&Bh[cur][wc * 64 + i * 16 + lr][sl * 8];
            b_l[i] = *(const bf16x8*)&Bl[cur][wc * 64 + i * 16 + lr][sl * 8];
        }
#pragma unroll
        for (int i = 0; i < 4; i++)
#pragma unroll
            for (int j = 0; j < 4; j++) {
                acc[i][j] = __builtin_amdgcn_mfma_f32_16x16x32_bf16(a_h[i], b_h[j], acc[i][j], 0, 0, 0);
                acc[i][j] = __builtin_amdgcn_mfma_f32_16x16x32_bf16(a_h[i], b_l[j], acc[i][j], 0, 0, 0);
                acc[i][j] = __builtin_amdgcn_mfma_f32_16x16x32_bf16(a_l[i], b_h[j], acc[i][j], 0, 0, 0);
            }
        __syncthreads();   // drains prefetch (vmcnt 0) + fences buffer reuse
        cur ^= 1;
    }

    const int N = gridDim.x * 128;
#pragma unroll
    for (int i = 0; i < 4; i++)
#pragma unroll
        for (int j = 0; j < 4; j++) {
            int n = n0 + wc * 64 + j * 16 + lr;
            float bv = bias ? bias[n] : 0.f;
#pragma unroll
            for (int rr = 0; rr < 4; rr++) {
                int m = m0 + wr * 64 + i * 16 + lg * 4 + rr;
                float v = acc[i][j][rr] + bv;
                if (ACT == 1) {
                    v = sigmoidf_(v);
                } else if (ACT == 2) {
                    v = sigmoidf_(v) * (1.f - aux[(size_t)m * N + n]);
                } else if (ACT == 3) {
                    float zz = v * sigmoidf_(v);
                    float uu = zz * aux[(size_t)m * N + n];
                    ushort_t uh, ul;
                    hl_split(uu, uh, ul);
                    Uhi[(size_t)m * N + n] = uh;
                    Ulo[(size_t)m * N + n] = ul;
                }
                if (ACT != 3) C0[(size_t)m * N + n] = v;
            }
        }
}

// ---------------------------------------------------------------------------
// conv_beta: beta = gate * causal_conv(ihp), in place over gate.
// ---------------------------------------------------------------------------
__global__ __launch_bounds__(256)
void conv_beta(const float* __restrict__ ihp, float* gate_beta,
               const float* __restrict__ cw, const float* __restrict__ cb)
{
    int gid = blockIdx.x * 256 + threadIdx.x;   // over M_*DH/4
    int c4  = gid & 511;
    int row = gid >> 9;
    int t   = row & (T_ - 1);
    const float4* ih4 = (const float4*)ihp;
    float4 g = ((const float4*)gate_beta)[gid];
    int c0 = c4 * 4;
    float4 w0 = ((const float4*)cw)[c0 + 0];
    float4 w1 = ((const float4*)cw)[c0 + 1];
    float4 w2 = ((const float4*)cw)[c0 + 2];
    float4 w3 = ((const float4*)cw)[c0 + 3];
    float4 cbv = ((const float4*)cb)[c4];
    float4 v[4];
#pragma unroll
    for (int j = 0; j < 4; j++) {
        int tt = t + j - 3;
        if (tt >= 0) v[j] = ih4[(size_t)(row + j - 3) * 512 + c4];
        else         v[j] = make_float4(0.f, 0.f, 0.f, 0.f);
    }
    float4 ihc;
    ihc.x = cbv.x + w0.x * v[0].x + w0.y * v[1].x + w0.z * v[2].x + w0.w * v[3].x;
    ihc.y = cbv.y + w1.x * v[0].y + w1.y * v[1].y + w1.z * v[2].y + w1.w * v[3].y;
    ihc.z = cbv.z + w2.x * v[0].z + w2.y * v[1].z + w2.z * v[2].z + w2.w * v[3].z;
    ihc.w = cbv.w + w3.x * v[0].w + w3.y * v[1].w + w3.z * v[2].w + w3.w * v[3].w;
    float4 beta;
    beta.x = g.x * ihc.x;  beta.y = g.y * ihc.y;
    beta.z = g.z * ihc.z;  beta.w = g.w * ihc.w;
    ((float4*)gate_beta)[gid] = beta;
}

// ---------------------------------------------------------------------------
// 3-phase chunked linear scan: h_t = alpha_t*h_{t-1} + beta_t
// ---------------------------------------------------------------------------
__global__ __launch_bounds__(256)
void scan_phaseA(const float* __restrict__ alpha, const float* __restrict__ beta,
                 float* __restrict__ sA, float* __restrict__ sB)
{
    int gid  = blockIdx.x * 256 + threadIdx.x;   // B_*DH*NC
    int c    = gid & (DH - 1);
    int rest = gid >> 11;
    int chunk = rest & (NC - 1);
    int b    = rest >> 6;
    size_t base = ((size_t)(b * T_ + chunk * CL)) * DH + c;
    float Ar = 1.f, Br = 0.f;
    for (int l = 0; l < CL; l++) {
        float al = alpha[base + (size_t)l * DH];
        float be = beta [base + (size_t)l * DH];
        Ar *= al;
        Br = Br * al + be;
    }
    int si = chunk * (B_ * DH) + b * DH + c;
    sA[si] = Ar; sB[si] = Br;
}

__global__ __launch_bounds__(256)
void scan_phaseB(const float* __restrict__ sA, const float* __restrict__ sB,
                 float* __restrict__ hinit)
{
    int gid = blockIdx.x * 256 + threadIdx.x;    // B_*DH
    int c = gid & (DH - 1); int b = gid >> 11;
    float h = 0.f;
    for (int ch = 0; ch < NC; ch++) {
        int si = ch * (B_ * DH) + b * DH + c;
        hinit[si] = h;
        h = sA[si] * h + sB[si];
    }
}

// phaseC writes h over beta (same buffer) — read-then-write per element.
__global__ __launch_bounds__(256)
void scan_phaseC(const float* __restrict__ alpha, const float* beta,
                 const float* __restrict__ hinit, float* hout)
{
    int gid  = blockIdx.x * 256 + threadIdx.x;
    int c    = gid & (DH - 1);
    int rest = gid >> 11;
    int chunk = rest & (NC - 1);
    int b    = rest >> 6;
    size_t base = ((size_t)(b * T_ + chunk * CL)) * DH + c;
    float h = hinit[chunk * (B_ * DH) + b * DH + c];
    for (int l = 0; l < CL; l++) {
        float al = alpha[base + (size_t)l * DH];
        float be = beta [base + (size_t)l * DH];
        h = al * h + be;
        hout[base + (size_t)l * DH] = h;
    }
}

// ---------------------------------------------------------------------------
// LayerNorm over DH, in place: h -> (h-mu)*rsqrt(var+eps)*g + b
// ---------------------------------------------------------------------------
__global__ __launch_bounds__(256)
void ln_inplace(float* h, const float* __restrict__ g, const float* __restrict__ bl)
{
    int row = blockIdx.x;
    int tid = threadIdx.x;
    float4* h4 = (float4*)(h + (size_t)row * DH);
    float4 v0 = h4[tid], v1 = h4[tid + 256];
    float s = v0.x + v0.y + v0.z + v0.w + v1.x + v1.y + v1.z + v1.w;
    float q = v0.x * v0.x + v0.y * v0.y + v0.z * v0.z + v0.w * v0.w
            + v1.x * v1.x + v1.y * v1.y + v1.z * v1.z + v1.w * v1.w;
#pragma unroll
    for (int o = 32; o; o >>= 1) { s += __shfl_down(s, o); q += __shfl_down(q, o); }
    __shared__ float rs[4], rq[4];
    int wid = tid >> 6, lane = tid & 63;
    if (lane == 0) { rs[wid] = s; rq[wid] = q; }
    __syncthreads();
    s = rs[0] + rs[1] + rs[2] + rs[3];
    q = rq[0] + rq[1] + rq[2] + rq[3];
    float mu  = s * (1.f / DH);
    float var = q * (1.f / DH) - mu * mu;
    float ri  = rsqrtf(var + 1e-5f);
    const float4* g4 = (const float4*)g;
    const float4* b4 = (const float4*)bl;
    {
        float4 gg = g4[tid], bb = b4[tid], o;
        o.x = (v0.x - mu) * ri * gg.x + bb.x;
        o.y = (v0.y - mu) * ri * gg.y + bb.y;
        o.z = (v0.z - mu) * ri * gg.z + bb.z;
        o.w = (v0.w - mu) * ri * gg.w + bb.w;
        h4[tid] = o;
    }
    {
        float4 gg = g4[tid + 256], bb = b4[tid + 256], o;
        o.x = (v1.x - mu) * ri * gg.x + bb.x;
        o.y = (v1.y - mu) * ri * gg.y + bb.y;
        o.z = (v1.z - mu) * ri * gg.z + bb.z;
        o.w = (v1.w - mu) * ri * gg.w + bb.w;
        h4[tid + 256] = o;
    }
}

// Combined output bias: bc = W_out_b @ out_w + out_b
__global__ __launch_bounds__(256)
void bc_kernel(const float* __restrict__ wob, const float* __restrict__ ow,
               const float* __restrict__ ob, float* __restrict__ bc)
{
    int n = blockIdx.x * 256 + threadIdx.x;      // DM
    float acc = ob[n];
    for (int k = 0; k < DH; k++) acc += wob[k] * ow[(size_t)k * DM + n];
    bc[n] = acc;
}

extern "C" void kernel_launch(void* const* d_in, const int* in_sizes, int n_in,
                              void* d_out, int out_size, void* d_ws, size_t ws_size,
                              hipStream_t stream)
{
    const float* x   = (const float*)d_in[0];
    const float* Wih = (const float*)d_in[1];
    const float* bih = (const float*)d_in[2];
    const float* Wg  = (const float*)d_in[3];
    const float* bg  = (const float*)d_in[4];
    const float* Wd  = (const float*)d_in[5];
    const float* bd  = (const float*)d_in[6];
    const float* Wz  = (const float*)d_in[7];
    const float* bz  = (const float*)d_in[8];
    const float* cw  = (const float*)d_in[9];
    const float* cb  = (const float*)d_in[10];
    const float* lng = (const float*)d_in[11];
    const float* lnb = (const float*)d_in[12];
    const float* Wow = (const float*)d_in[13];
    const float* Wob = (const float*)d_in[14];
    const float* ow  = (const float*)d_in[15];
    const float* ob  = (const float*)d_in[16];
    float* out = (float*)d_out;

    // ---- workspace layout: 211 MiB + 4 KiB total ----
    // xhi/xlo (32 MiB) OVERLAY d_out: live steps 1..9; d_out written only in
    // step 10 (after xhi/xlo are dead).  d_out = M_*DM*4B = 32 MiB exactly.
    char* p = (char*)d_ws;
    float* R0 = (float*)(p);                              // 64 MiB: ihp (dead after conv)
    float* R1 = (float*)(p + ((size_t)64  << 20));        // 64 MiB: gate->beta->h->hn
    float* R2 = (float*)(p + ((size_t)128 << 20));        // 64 MiB: alpha (dead after scan)
    ushort_t* Wsh = (ushort_t*)(p + ((size_t)192 << 20)); //  8 MiB (weight slot hi)
    ushort_t* Wsl = (ushort_t*)(p + ((size_t)200 << 20)); //  8 MiB (weight slot lo)
    float* sA    = (float*)(p + ((size_t)208 << 20));     //  1 MiB
    float* sB    = (float*)(p + ((size_t)209 << 20));     //  1 MiB
    float* hinit = (float*)(p + ((size_t)210 << 20));     //  1 MiB
    float* bc    = (float*)(p + ((size_t)211 << 20));     //  4 KiB
    ushort_t* xhi = (ushort_t*)d_out;                            // 16 MiB (overlay)
    ushort_t* xlo = (ushort_t*)((char*)d_out + ((size_t)16 << 20)); // 16 MiB (overlay)
    // R0 sub-region (valid after conv_beta):
    ushort_t* wowh = (ushort_t*)R0;                              // 8 MiB
    ushort_t* wowl = (ushort_t*)((char*)R0 + ((size_t)8  << 20));// 8 MiB
    ushort_t* owth = (ushort_t*)((char*)R0 + ((size_t)16 << 20));// 4 MiB
    ushort_t* owtl = (ushort_t*)((char*)R0 + ((size_t)20 << 20));// 4 MiB
    float*    Wc   = (float*)   ((char*)R0 + ((size_t)24 << 20));// 8 MiB [2048][1024]
    ushort_t* Wcth = (ushort_t*)((char*)R0 + ((size_t)32 << 20));// 4 MiB [1024][2048]
    ushort_t* Wctl = (ushort_t*)((char*)R0 + ((size_t)36 << 20));// 4 MiB
    // R2 sub-region (valid after scan):
    ushort_t* uhi = (ushort_t*)R2;                               // 32 MiB
    ushort_t* ulo = (ushort_t*)((char*)R2 + ((size_t)32 << 20)); // 32 MiB

    // 1. split x -> bf16 hi/lo (into d_out overlay)
    split_hi_lo<<<(M_ * DM / 4) / 256, 256, 0, stream>>>(x, xhi, xlo);

    // 2. ihp = x@Wih + bih (raw preact)
    split_t<<<dim3(DH / 32, DM / 32), 256, 0, stream>>>(Wih, Wsh, Wsl, DM, DH);
    mfma_gemm<0><<<dim3(DH / 128, M_ / 128), 256, 0, stream>>>(
        xhi, xlo, Wsh, Wsl, DM, R0, bih, nullptr, nullptr, nullptr);

    // 3. gate = sigmoid(x@Wg + bg)
    split_t<<<dim3(DH / 32, DM / 32), 256, 0, stream>>>(Wg, Wsh, Wsl, DM, DH);
    mfma_gemm<1><<<dim3(DH / 128, M_ / 128), 256, 0, stream>>>(
        xhi, xlo, Wsh, Wsl, DM, R1, bg, nullptr, nullptr, nullptr);

    // 4. alpha = sigmoid(x@Wd + bd) * (1 - gate)
    split_t<<<dim3(DH / 32, DM / 32), 256, 0, stream>>>(Wd, Wsh, Wsl, DM, DH);
    mfma_gemm<2><<<dim3(DH / 128, M_ / 128), 256, 0, stream>>>(
        xhi, xlo, Wsh, Wsl, DM, R2, bd, R1, nullptr, nullptr);

    // 5. beta = gate * conv(ihp)   (in place over gate; ihp dead after this)
    conv_beta<<<(M_ * DH / 4) / 256, 256, 0, stream>>>(R0, R1, cw, cb);

    // 6. chunked linear scan -> h over beta (R1)
    scan_phaseA<<<(B_ * DH * NC) / 256, 256, 0, stream>>>(R2, R1, sA, sB);
    scan_phaseB<<<(B_ * DH) / 256, 256, 0, stream>>>(sA, sB, hinit);
    scan_phaseC<<<(B_ * DH * NC) / 256, 256, 0, stream>>>(R2, R1, hinit, R1);

    // 7. LayerNorm in place (R1: h -> hn)
    ln_inplace<<<M_, 256, 0, stream>>>(R1, lng, lnb);

    // 8. Wc = Wow @ ow  (folded output weight), bc = Wob@ow + ob
    split_hi_lo<<<((size_t)DH * DH / 4) / 256, 256, 0, stream>>>(Wow, wowh, wowl);
    split_t<<<dim3(DM / 32, DH / 32), 256, 0, stream>>>(ow, owth, owtl, DH, DM);
    mfma_gemm<0><<<dim3(DM / 128, DH / 128), 256, 0, stream>>>(
        wowh, wowl, owth, owtl, DH, Wc, nullptr, nullptr, nullptr, nullptr);
    split_t<<<dim3(DM / 32, DH / 32), 256, 0, stream>>>(Wc, Wcth, Wctl, DH, DM);
    bc_kernel<<<DM / 256, 256, 0, stream>>>(Wob, ow, ob, bc);

    // 9. z GEMM fused: u = silu(x@Wz + bz) * hn, split -> uhi/ulo (over R2)
    split_t<<<dim3(DH / 32, DM / 32), 256, 0, stream>>>(Wz, Wsh, Wsl, DM, DH);
    mfma_gemm<3><<<dim3(DH / 128, M_ / 128), 256, 0, stream>>>(
        xhi, xlo, Wsh, Wsl, DM, nullptr, bz, R1, uhi, ulo);

    // 10. out = u @ Wc + bc   (xhi/xlo dead; d_out now becomes the real output)
    mfma_gemm<0><<<dim3(DM / 128, M_ / 128), 256, 0, stream>>>(
        uhi, ulo, Wcth, Wctl, DH, out, bc, nullptr, nullptr, nullptr);
}